// Round 11
// baseline (163.870 us; speedup 1.0000x reference)
//
#include <hip/hip_runtime.h>

#define B_ 4
#define C_ 256
#define N_ 4096
#define D_ 64

typedef __bf16 bf16x8 __attribute__((ext_vector_type(8)));
typedef float floatx4 __attribute__((ext_vector_type(4)));
typedef float floatx16 __attribute__((ext_vector_type(16)));
typedef unsigned short ushort8v __attribute__((ext_vector_type(8)));
typedef unsigned short ushort4v __attribute__((ext_vector_type(4)));
typedef unsigned short ushort2v __attribute__((ext_vector_type(2)));

static __device__ __forceinline__ unsigned short f2bf(float f) {
    unsigned int u = __builtin_bit_cast(unsigned int, f);
    u += 0x7fffu + ((u >> 16) & 1u);   // RNE
    return (unsigned short)(u >> 16);
}
static __device__ __forceinline__ float bf2f(unsigned short h) {
    unsigned int u = ((unsigned int)h) << 16;
    return __builtin_bit_cast(float, u);
}
// HW packed f32x2 -> bf16x2 (RNE), 1 VALU op; src0 -> low half
static __device__ __forceinline__ unsigned int cvt_pk_bf16(float lo, float hi) {
    unsigned int d;
    asm("v_cvt_pk_bf16_f32 %0, %1, %2" : "=v"(d) : "v"(lo), "v"(hi));
    return d;
}

// async global->LDS DMA, 16B/lane, dst = wave-uniform base + lane*16,
// src = PER-LANE global address (enables transposed staging).
#define GLOAD16(gp, lp)                                                      \
    __builtin_amdgcn_global_load_lds(                                        \
        (const __attribute__((address_space(1))) void*)(gp),                 \
        (__attribute__((address_space(3))) void*)(lp), 16, 0, 0)

// ---------------------------------------------------------------------------
// Fused pre-pass:
//  (a) all 256 blocks: transpose one 64n x 256c x-tile to Xt[b][n][c] bf16
//      (swizzled-LDS transpose — staging code identical to the verified
//      proj staging; readout b128 conflict-free).
//  (b) first 96 blocks additionally run the convert_w body (A-frag-native
//      WbfA) — saves a dispatch.
// ---------------------------------------------------------------------------
__global__ __launch_bounds__(256, 4) void xtw_kernel(
    const float* __restrict__ x,
    const float* __restrict__ Wq, const float* __restrict__ Wk,
    const float* __restrict__ Wv,
    unsigned short* __restrict__ WbfA, unsigned short* __restrict__ Xt)
{
    __shared__ __align__(16) unsigned short xs[64 * 264];   // 33792 B

    const int n0 = blockIdx.x * 64;
    const int b  = blockIdx.y;
    const int t  = threadIdx.x;
    const int gid = blockIdx.x + 64 * blockIdx.y;

    // ---- W conversion (96 blocks' worth of work) ----
    if (gid < 96) {
        int tid = gid * 256 + t;                // 0..24575
        int p0  = tid * 4;
        int j0   = p0 & 7;
        int lane = (p0 >> 3) & 63;
        int sidx = p0 >> 9;
        int ft = sidx >> 3, ks = sidx & 7;
        int m  = lane & 15, g = lane >> 4;
        int f  = 16*ft + m;
        int c  = 32*ks + 8*g + j0;
        const float* src = (f < 64)  ? (Wq + (size_t)f * C_)
                         : (f < 128) ? (Wk + (size_t)(f - 64) * C_)
                                     : (Wv + (size_t)(f - 128) * C_);
        float4 v = *(const float4*)(src + c);
        uint2 u;
        u.x = cvt_pk_bf16(v.x, v.y);
        u.y = cvt_pk_bf16(v.z, v.w);
        *(uint2*)(WbfA + p0) = u;
    }

    // ---- stage x tile -> LDS bf16, swizzled (verbatim-verified pattern) ----
#pragma unroll
    for (int k = 0; k < 8; ++k) {
        int e  = t + 256 * k;           // 0..2047
        int cp = e >> 4;                // 0..127
        int c  = 2 * cp;
        int n4 = (e & 15) * 4;
        float4 v0 = *(const float4*)(x + ((size_t)b*C_ + c    )*N_ + n0 + n4);
        float4 v1 = *(const float4*)(x + ((size_t)b*C_ + c + 1)*N_ + n0 + n4);
        float a0[4] = {v0.x, v0.y, v0.z, v0.w};
        float a1[4] = {v1.x, v1.y, v1.z, v1.w};
#pragma unroll
        for (int j = 0; j < 4; ++j) {
            int n = n4 + j;
            unsigned int u = cvt_pk_bf16(a0[j], a1[j]);
            *(unsigned int*)&xs[n*264 + (((c >> 3) ^ (n & 7)) << 3) + (c & 7)] = u;
        }
    }
    __syncthreads();

    // ---- write out transposed: Xt[b][n0+n][c], 16B per lane, coalesced ----
#pragma unroll
    for (int pass = 0; pass < 8; ++pass) {
        int n  = 8*pass + (t >> 5);
        int cc = t & 31;                // c-chunk of 8
        ushort8v v = *(const ushort8v*)&xs[n*264 + ((cc ^ (n & 7)) << 3)];
        *(ushort8v*)(Xt + ((size_t)b*N_ + n0 + n)*256 + 8*cc) = v;
    }
}

// ---------------------------------------------------------------------------
// MFMA projection: B-tile staged by pure global_load_lds DMA from Xt in
// B-frag-native layout (per-lane transposed source — flash STAGE_V pattern).
// Zero staging VALU, zero LDS-write traffic, lane-linear conflict-free
// ds_read_b128 frag reads. A-frags coalesced from WbfA. Epilogue/gather
// verbatim R10 (verified).
// ---------------------------------------------------------------------------
__global__ __launch_bounds__(256, 4) void proj_kernel(
    const unsigned short* __restrict__ Xt, const unsigned short* __restrict__ WbfA,
    const float* __restrict__ bq, const float* __restrict__ bk,
    const float* __restrict__ bv,
    unsigned short* __restrict__ Qg, unsigned short* __restrict__ Kg,
    unsigned short* __restrict__ Vg)
{
    __shared__ __align__(16) unsigned short xslds[32 * 512];  // 32 KB
    unsigned short* Lt = xslds;        // epilogue overlay [128][72]

    const int n0 = blockIdx.x * 64;
    const int f0 = blockIdx.y * 128;
    const int b  = blockIdx.z;
    const int t  = threadIdx.x;
    const int w  = t >> 6;             // 0..3
    const int lane = t & 63;
    const int g  = lane >> 4;
    const int m  = lane & 15;

    // ---- DMA-stage x B-tile: slot (nt=w, ks=u) holds
    //      Xt[n0+16nt+(l&15)][32ks+8(l>>4) .. +7]  (B-frag-native) ----
#pragma unroll
    for (int u = 0; u < 8; ++u) {
        const unsigned short* gp = Xt
            + ((size_t)b*N_ + n0 + 16*w + m)*256 + 32*u + 8*g;
        GLOAD16(gp, &xslds[(w*8 + u) * 512]);
    }

    float bias_[2][4];
#pragma unroll
    for (int mt = 0; mt < 2; ++mt)
#pragma unroll
        for (int r = 0; r < 4; ++r) {
            int fg = f0 + 32*w + 16*mt + 4*g + r;
            bias_[mt][r] = (fg < 64) ? bq[fg]
                         : (fg < 128) ? bk[fg - 64] : bv[fg - 128];
        }

    // A-frag segment bases (coalesced, L2-hot)
    const unsigned short* Wa0 = WbfA + (size_t)(((f0 >> 4) + 2*w    )*8)*512
                              + lane*8;
    const unsigned short* Wa1 = WbfA + (size_t)(((f0 >> 4) + 2*w + 1)*8)*512
                              + lane*8;

    floatx4 acc[2][4];
#pragma unroll
    for (int mt = 0; mt < 2; ++mt)
#pragma unroll
        for (int nt = 0; nt < 4; ++nt) acc[mt][nt] = (floatx4){0.f,0.f,0.f,0.f};

    __syncthreads();   // x tile staged (drains DMA)

#pragma unroll
    for (int ks = 0; ks < 8; ++ks) {
        bf16x8 af[2];
        af[0] = *(const bf16x8*)(Wa0 + ks*512);
        af[1] = *(const bf16x8*)(Wa1 + ks*512);
#pragma unroll
        for (int nt = 0; nt < 4; ++nt) {
            bf16x8 bfr = *(const bf16x8*)&xslds[(nt*8 + ks)*512 + lane*8];
#pragma unroll
            for (int mt = 0; mt < 2; ++mt)
                acc[mt][nt] = __builtin_amdgcn_mfma_f32_16x16x32_bf16(
                                  af[mt], bfr, acc[mt][nt], 0, 0, 0);
        }
    }

    __syncthreads();   // xslds dead -> Lt overlay

#pragma unroll
    for (int mt = 0; mt < 2; ++mt)
#pragma unroll
        for (int nt = 0; nt < 4; ++nt)
#pragma unroll
            for (int r = 0; r < 4; ++r)
                Lt[(32*w + 16*mt + 4*g + r)*72 + 16*nt + m] =
                    f2bf(acc[mt][nt][r] + bias_[mt][r]);
    __syncthreads();

    if (f0 == 0) {
        // vectorized transpose gather (R10, verified)
        const int fq0 = (t >> 4) * 8;       // 0,8,...,120
        const int nl4 = (t & 15) * 4;       // 0,4,...,60
        ushort4v col[8];
#pragma unroll
        for (int j = 0; j < 8; ++j)
            col[j] = *(const ushort4v*)&Lt[(fq0 + j)*72 + nl4];
#pragma unroll
        for (int c = 0; c < 4; ++c) {
            ushort8v u;
#pragma unroll
            for (int j = 0; j < 8; ++j) u[j] = col[j][c];
            int nl = nl4 + c;
            unsigned short* dst = (fq0 < 64)
                ? (Qg + ((size_t)b*N_ + n0 + nl)*D_ + fq0)
                : (Kg + ((size_t)b*N_ + n0 + nl)*D_ + (fq0 - 64));
            *(ushort8v*)dst = u;
        }
    } else {
        const int cb = f0 - 128;
#pragma unroll
        for (int k = 0; k < 4; ++k) {
            int e  = t + 256 * k;
            int fr = e >> 3;
            int n8 = (e & 7) * 8;
            ushort8v u = *(const ushort8v*)&Lt[fr*72 + n8];
            *(ushort8v*)(Vg + ((size_t)b*C_ + cb + fr)*N_ + n0 + n8) = u;
        }
    }
}

// ---------------------------------------------------------------------------
// Flash attention 32x32x16 + one-tile-lag PV pipeline + defer-max
// (R9/R10 verbatim — 69.3 us measured, PASSED).
// ---------------------------------------------------------------------------
__global__ __launch_bounds__(512, 2) void flash_kernel(
    const unsigned short* __restrict__ Qg, const unsigned short* __restrict__ Kg,
    const unsigned short* __restrict__ Vg,
    unsigned short* __restrict__ Opart, float* __restrict__ ML)
{
    __shared__ __align__(16) unsigned short Vlds[3][32 * 512];  // 96 KB
    __shared__ __align__(16) unsigned short Klds[2][8 * 512];   // 16 KB
    __shared__ float AL[8][32];                                 //  1 KB

    const int gx   = blockIdx.x;        // quarter + 4*b (XCD pin: gx%8)
    const int tile = blockIdx.y;        // 0..15 (256-query tiles)
    const int quarter = gx & 3;
    const int b    = gx >> 2;
    const int n0   = tile * 256;
    const int t    = threadIdx.x;
    const int w    = t >> 6;            // 0..7
    const int lane = t & 63;
    const int q32  = lane & 31;         // query within wave / col index
    const int h    = lane >> 5;         // lane half

    const unsigned short* Qb = Qg + ((size_t)b*N_ + n0)*D_;
    const unsigned short* Kb = Kg + (size_t)b*N_*D_;
    const unsigned short* Vb = Vg + (size_t)b*C_*N_;

    const int cstart = quarter * 16;
    const int cend   = cstart + 16;

    // Q B-frags (stationary): col=q32, k=8h+j per 16-chunk ks
    bf16x8 qf[4];
#pragma unroll
    for (int ks = 0; ks < 4; ++ks)
        qf[ks] = *(const bf16x8*)(Qb + (size_t)(32*w + q32)*D_ + 16*ks + 8*h);

    floatx16 accO[8];
#pragma unroll
    for (int ct = 0; ct < 8; ++ct)
#pragma unroll
        for (int r = 0; r < 16; ++r) accO[ct][r] = 0.f;

    float mrow = -1e30f, lrow = 0.f;
    bf16x8 pa_prev[4];
    bool skip_prev = true;              // no pending PV before first iter

#define STAGE_K(T64, BUF) do {                                               \
    const unsigned short* gp = Kb                                            \
        + (size_t)((T64)*64 + 32*(w >> 2) + q32)*D_ + 16*(w & 3) + 8*h;      \
    GLOAD16(gp, &Klds[BUF][w * 512]); } while (0)

#define STAGE_V(T64, BUF) do {                                               \
    _Pragma("unroll")                                                        \
    for (int u_ = 0; u_ < 4; ++u_) {                                         \
        const unsigned short* gp = Vb                                        \
            + (size_t)(32*w + q32)*N_ + (T64)*64 + 16*u_ + 8*h;              \
        GLOAD16(gp, &Vlds[BUF][(w*4 + u_) * 512]);                           \
    } } while (0)

#define FITER(T64, HASPV, HASPRE) do {                                       \
    if (HASPRE) { STAGE_K((T64)+1, kcur ^ 1); STAGE_V((T64)+1, vnxt); }      \
    /* ST(T64) = K*Q */                                                      \
    floatx16 accS[2];                                                        \
    _Pragma("unroll")                                                        \
    for (int kt = 0; kt < 2; ++kt)                                           \
        _Pragma("unroll")                                                    \
        for (int r = 0; r < 16; ++r) accS[kt][r] = 0.f;                      \
    _Pragma("unroll")                                                        \
    for (int kt = 0; kt < 2; ++kt)                                           \
        _Pragma("unroll")                                                    \
        for (int ks = 0; ks < 4; ++ks) {                                     \
            bf16x8 kfr = *(const bf16x8*)                                    \
                &Klds[kcur][(kt*4 + ks)*512 + lane*8];                       \
            accS[kt] = __builtin_amdgcn_mfma_f32_32x32x16_bf16(              \
                           kfr, qf[ks], accS[kt], 0, 0, 0);                  \
        }                                                                    \
    /* PV(T64-1): independent of softmax below -> overlaps it */             \
    if (HASPV) {                                                             \
        if (!skip_prev) {                                                    \
            float4 av_[4];                                                   \
            _Pragma("unroll")                                                \
            for (int gp_ = 0; gp_ < 4; ++gp_)                                \
                av_[gp_] = *(const float4*)&AL[w][8*gp_ + 4*h];              \
            _Pragma("unroll")                                                \
            for (int ct = 0; ct < 8; ++ct)                                   \
                _Pragma("unroll")                                            \
                for (int gp_ = 0; gp_ < 4; ++gp_)                            \
                    _Pragma("unroll")                                        \
                    for (int i_ = 0; i_ < 4; ++i_)                           \
                        accO[ct][4*gp_ + i_] *= av_[gp_][i_];                \
        }                                                                    \
        __builtin_amdgcn_s_setprio(1);                                       \
        _Pragma("unroll")                                                    \
        for (int ct = 0; ct < 8; ++ct)                                       \
            _Pragma("unroll")                                                \
            for (int kc = 0; kc < 4; ++kc) {                                 \
                bf16x8 vf = *(const bf16x8*)                                 \
                    &Vlds[vprv][(ct*4 + kc)*512 + lane*8];                   \
                accO[ct] = __builtin_amdgcn_mfma_f32_32x32x16_bf16(          \
                               pa_prev[kc], vf, accO[ct], 0, 0, 0);          \
            }                                                                \
        __builtin_amdgcn_s_setprio(0);                                       \
    }                                                                        \
    /* softmax(T64): 32 scores/lane + defer-max */                           \
    float mx = -1e30f;                                                       \
    _Pragma("unroll")                                                        \
    for (int kt = 0; kt < 2; ++kt)                                           \
        _Pragma("unroll")                                                    \
        for (int r = 0; r < 16; ++r) mx = fmaxf(mx, accS[kt][r]);            \
    mx = fmaxf(mx, __shfl_xor(mx, 32));                                      \
    bool skip = __all(mx <= mrow + 8.f) != 0;                                \
    float mnew  = skip ? mrow : fmaxf(mrow, mx);                             \
    float alpha = __expf(mrow - mnew);                                       \
    mrow = mnew;                                                             \
    float p_[2][16];                                                         \
    float rs = 0.f;                                                          \
    _Pragma("unroll")                                                        \
    for (int kt = 0; kt < 2; ++kt)                                           \
        _Pragma("unroll")                                                    \
        for (int r = 0; r < 16; ++r) {                                       \
            float e_ = __expf(accS[kt][r] - mnew);                           \
            p_[kt][r] = e_;                                                  \
            rs += e_;                                                        \
        }                                                                    \
    rs += __shfl_xor(rs, 32);                                                \
    lrow = lrow * alpha + rs;                                                \
    if (!skip && h == 0) AL[w][q32] = alpha;                                 \
    skip_prev = skip;                                                        \
    /* P -> PV A-frags in register (verified R8 mapping) */                  \
    _Pragma("unroll")                                                        \
    for (int kt = 0; kt < 2; ++kt)                                           \
        _Pragma("unroll")                                                    \
        for (int cp = 0; cp < 2; ++cp) {                                     \
            unsigned int Y0 = cvt_pk_bf16(p_[kt][8*cp + 0], p_[kt][8*cp + 1]);\
            unsigned int Y1 = cvt_pk_bf16(p_[kt][8*cp + 2], p_[kt][8*cp + 3]);\
            unsigned int X0 = cvt_pk_bf16(p_[kt][8*cp + 4], p_[kt][8*cp + 5]);\
            unsigned int X1 = cvt_pk_bf16(p_[kt][8*cp + 6], p_[kt][8*cp + 7]);\
            asm volatile("v_permlane32_swap_b32 %0, %1" : "+v"(Y0), "+v"(X0));\
            asm volatile("v_permlane32_swap_b32 %0, %1" : "+v"(Y1), "+v"(X1));\
            uint4 fu; fu.x = Y0; fu.y = Y1; fu.z = X0; fu.w = X1;            \
            pa_prev[kt*2 + cp] = __builtin_bit_cast(bf16x8, fu);             \
        }                                                                    \
    __syncthreads();  /* drains prefetch DMA; fences buffer rotation */      \
    vprv = vcur; vcur = vnxt; vnxt = (vnxt + 1 == 3) ? 0 : vnxt + 1;         \
    kcur ^= 1;                                                               \
} while (0)

    // prologue: stage tile cstart
    STAGE_K(cstart, 0);
    STAGE_V(cstart, 0);
    __syncthreads();

    int vcur = 0, vnxt = 1, vprv = 2, kcur = 0;

    FITER(cstart, 0, 1);                              // first: no PV yet
    for (int t64 = cstart + 1; t64 < cend - 1; ++t64)
        FITER(t64, 1, 1);                             // 14 steady iterations
    FITER(cend - 1, 1, 0);                            // last: no prefetch

    // epilogue: PV(cend-1)
    if (!skip_prev) {
        float4 av_[4];
#pragma unroll
        for (int gp_ = 0; gp_ < 4; ++gp_)
            av_[gp_] = *(const float4*)&AL[w][8*gp_ + 4*h];
#pragma unroll
        for (int ct = 0; ct < 8; ++ct)
#pragma unroll
            for (int gp_ = 0; gp_ < 4; ++gp_)
#pragma unroll
                for (int i_ = 0; i_ < 4; ++i_)
                    accO[ct][4*gp_ + i_] *= av_[gp_][i_];
    }
#pragma unroll
    for (int ct = 0; ct < 8; ++ct)
#pragma unroll
        for (int kc = 0; kc < 4; ++kc) {
            bf16x8 vf = *(const bf16x8*)
                &Vlds[vprv][(ct*4 + kc)*512 + lane*8];
            accO[ct] = __builtin_amdgcn_mfma_f32_32x32x16_bf16(
                           pa_prev[kc], vf, accO[ct], 0, 0, 0);
        }

    // store unnormalized partial O (bf16) + per-query m,l
    const size_t tbase = ((size_t)(quarter*B_ + b)*16 + tile);
    unsigned short* Ob = Opart + tbase * (C_ * 256);
    float* ml = ML + tbase * 512;

    if (h == 0) {
        ml[32*w + q32]       = mrow;
        ml[256 + 32*w + q32] = lrow;
    }

#pragma unroll
    for (int ct = 0; ct < 8; ++ct) {
        int c = 32*ct + q32;
#pragma unroll
        for (int gp = 0; gp < 4; ++gp) {
            uint2 pu;
            pu.x = cvt_pk_bf16(accO[ct][4*gp + 0], accO[ct][4*gp + 1]);
            pu.y = cvt_pk_bf16(accO[ct][4*gp + 2], accO[ct][4*gp + 3]);
            *(uint2*)(Ob + (size_t)c*256 + 32*w + 8*gp + 4*h) = pu;
        }
    }
#undef FITER
#undef STAGE_K
#undef STAGE_V
}

// ---------------------------------------------------------------------------
// Combine: S=4 static, 256-query tiles, 32 channels per block (R10 verbatim).
// ---------------------------------------------------------------------------
__global__ __launch_bounds__(256) void combine_kernel(
    const unsigned short* __restrict__ Opart, const float* __restrict__ ML,
    const float* __restrict__ x, const float* __restrict__ gamma,
    float* __restrict__ out)
{
    __shared__ float sc[4][256];
    const int tile   = blockIdx.x;      // 0..15
    const int cslice = blockIdx.y;      // 0..7
    const int b      = blockIdx.z;
    const int n0     = tile * 256;
    const int t      = threadIdx.x;     // 0..255 (= query for phase 1)

    {
        float mm[4], ll[4];
        float M = -1e30f;
#pragma unroll
        for (int s = 0; s < 4; ++s) {
            const float* mls = ML + ((size_t)(s*B_ + b)*16 + tile)*512;
            mm[s] = mls[t];
            ll[s] = mls[256 + t];
            M = fmaxf(M, mm[s]);
        }
        float fs[4];
        float L = 0.f;
#pragma unroll
        for (int s = 0; s < 4; ++s) { fs[s] = __expf(mm[s] - M); L += fs[s]*ll[s]; }
        float gm = gamma[0];
#pragma unroll
        for (int s = 0; s < 4; ++s) sc[s][t] = gm * fs[s] / L;
    }
    __syncthreads();

    const int nq = t & 63;              // query-quad (float4 column)
    const int cl = t >> 6;              // 0..3
    const float* xb = x   + (size_t)b*C_*N_;
    float*       ob = out + (size_t)b*C_*N_;
    const unsigned short* Os[4];
#pragma unroll
    for (int s = 0; s < 4; ++s)
        Os[s] = Opart + ((size_t)(s*B_ + b)*16 + tile)*(C_*256);

    float sv[4][4];
#pragma unroll
    for (int s = 0; s < 4; ++s)
#pragma unroll
        for (int k = 0; k < 4; ++k) sv[s][k] = sc[s][4*nq + k];

#pragma unroll
    for (int i = 0; i < 8; ++i) {
        int c = 32*cslice + 4*i + cl;
        float4 x4 = *(const float4*)(xb + (size_t)c*N_ + n0 + 4*nq);
        float4 y = x4;
#pragma unroll
        for (int s = 0; s < 4; ++s) {
            ushort4v a4 = *(const ushort4v*)(Os[s] + (size_t)c*256 + 4*nq);
            y.x += sv[s][0]*bf2f(a4[0]);
            y.y += sv[s][1]*bf2f(a4[1]);
            y.z += sv[s][2]*bf2f(a4[2]);
            y.w += sv[s][3]*bf2f(a4[3]);
        }
        *(float4*)(ob + (size_t)c*N_ + n0 + 4*nq) = y;
    }
}

// ---------------------------------------------------------------------------
extern "C" void kernel_launch(void* const* d_in, const int* in_sizes, int n_in,
                              void* d_out, int out_size, void* d_ws, size_t ws_size,
                              hipStream_t stream) {
    const float* x     = (const float*)d_in[0];
    const float* Wq    = (const float*)d_in[1];
    const float* bq    = (const float*)d_in[2];
    const float* Wk    = (const float*)d_in[3];
    const float* bk    = (const float*)d_in[4];
    const float* Wv    = (const float*)d_in[5];
    const float* bv    = (const float*)d_in[6];
    const float* gamma = (const float*)d_in[7];
    float* out = (float*)d_out;

    // ws layout (~54.3 MB):
    unsigned short* Qg = (unsigned short*)d_ws;            // 2 MiB
    unsigned short* Kg = Qg + (size_t)B_*N_*D_;            // 2 MiB
    unsigned short* Vg = Kg + (size_t)B_*N_*D_;            // 8 MiB
    unsigned short* Op = Vg + (size_t)B_*C_*N_;            // 33.6 MiB (S=4)
    float* ML = (float*)(Op + (size_t)4*B_*16*C_*256);     // 512 KiB
    unsigned short* WbfA = (unsigned short*)(ML + (size_t)4*B_*16*512); // 192 KiB
    unsigned short* Xt = WbfA + (size_t)98304;             // 8 MiB

    xtw_kernel<<<dim3(64, 4), 256, 0, stream>>>(x, Wq, Wk, Wv, WbfA, Xt);
    proj_kernel<<<dim3(64, 3, 4), 256, 0, stream>>>(Xt, WbfA, bq, bk, bv,
                                                    Qg, Kg, Vg);
    flash_kernel<<<dim3(16, 16), 512, 0, stream>>>(Qg, Kg, Vg, Op, ML);
    combine_kernel<<<dim3(16, 8, 4), 256, 0, stream>>>(Op, ML, x, gamma, out);
}